// Round 4
// baseline (897.177 us; speedup 1.0000x reference)
//
#include <hip/hip_runtime.h>
#include <hip/hip_bf16.h>

// ---------------------------------------------------------------------------
// GCN 2-layer forward (f32 in/out), MFMA bf16 GEMMs:
//   x1 = relu( Ahat @ (X W1) + b1 ),  out = Ahat @ (x1 W2) + b2
//   return log_softmax(out), softmax(out)
// Round 9: agg1 column-sliced for XCD-L2 locality. Round-8 counters showed
// FETCH=407MB ~= 8 x h1 (51MB): every XCD's L2 fetched the whole h1 because
// node->XCD assignment is random. Now slice = blockIdx.x%8 (round-robin ->
// one XCD per slice) owns 32 of 256 cols: per-XCD distinct h1 bytes = 6.4MB
// (L2-resident), gather becomes L2-hit. Wave per (node,slice), 16 edges in
// flight (4 lanes/edge x 16B), shfl_xor tree reduce, grid-stride over nodes.
// ---------------------------------------------------------------------------

#define F_IN 512
#define HID  256
#define NCLS 40
#define NPAD 48

typedef __attribute__((ext_vector_type(8))) short bf16x8;
typedef __attribute__((ext_vector_type(4))) float floatx4;

__device__ inline unsigned short f2bf(float v) {
    unsigned u = __float_as_uint(v);
    u += 0x7fffu + ((u >> 16) & 1u);   // round-to-nearest-even
    return (unsigned short)(u >> 16);
}
__device__ inline float bf2f(unsigned short u) {
    return __uint_as_float(((unsigned)u) << 16);
}

__device__ inline void gload_lds16(const void* g, void* l) {
    __builtin_amdgcn_global_load_lds(
        (const __attribute__((address_space(1))) unsigned int*)g,
        (__attribute__((address_space(3))) unsigned int*)l, 16, 0, 0);
}

__device__ inline bf16x8 pack8(float4 f0, float4 f1) {
    bf16x8 r;
    r[0] = (short)f2bf(f0.x); r[1] = (short)f2bf(f0.y);
    r[2] = (short)f2bf(f0.z); r[3] = (short)f2bf(f0.w);
    r[4] = (short)f2bf(f1.x); r[5] = (short)f2bf(f1.y);
    r[6] = (short)f2bf(f1.z); r[7] = (short)f2bf(f1.w);
    return r;
}

// ---------------- edge dtype detect (int64 vs int32) ----------------
__global__ void detect64_kernel(const int* __restrict__ ei, int* __restrict__ flag) {
    __shared__ int any_nz;
    if (threadIdx.x == 0) any_nz = 0;
    __syncthreads();
    int nz = 0;
    for (int i = threadIdx.x; i < 4096; i += 256) {
        nz |= (ei[2 * i + 1] != 0);
    }
    if (nz) atomicOr(&any_nz, 1);
    __syncthreads();
    if (threadIdx.x == 0) *flag = any_nz ? 0 : 1;  // 1 => int64 layout
}

__device__ inline int edge_src(const int* ei, long long E, int e, int is64) {
    return is64 ? ei[2LL * e] : ei[e];
}
__device__ inline int edge_dst(const int* ei, long long E, int e, int is64) {
    return is64 ? ei[2LL * (E + e)] : ei[(int)E + e];
}

// ---------------- degree count ----------------
__global__ void count_kernel(const int* __restrict__ ei, int E,
                             const int* __restrict__ flag, int* __restrict__ cnt) {
    int e = blockIdx.x * 256 + threadIdx.x;
    if (e >= E) return;
    int is64 = *flag;
    int d = edge_dst(ei, E, e, is64);
    atomicAdd(&cnt[d], 1);
}

// ---------------- scan (3-phase) ----------------
__global__ __launch_bounds__(256) void scan_block_sums(const int* __restrict__ cnt,
                                                       int* __restrict__ blockSums, int Nn) {
    __shared__ int sdata[256];
    int b = blockIdx.x, t = threadIdx.x;
    int sum = 0;
    int i0 = b * 1024 + t * 4;
    for (int i = 0; i < 4; ++i) {
        int idx = i0 + i;
        if (idx < Nn) sum += cnt[idx];
    }
    sdata[t] = sum;
    __syncthreads();
    for (int s = 128; s > 0; s >>= 1) {
        if (t < s) sdata[t] += sdata[t + s];
        __syncthreads();
    }
    if (t == 0) blockSums[b] = sdata[0];
}

__global__ void scan_sums_kernel(int* __restrict__ blockSums, int nB,
                                 int* __restrict__ rowStart, int Nn) {
    if (threadIdx.x == 0 && blockIdx.x == 0) {
        int run = 0;
        for (int i = 0; i < nB; ++i) { int v = blockSums[i]; blockSums[i] = run; run += v; }
        rowStart[Nn] = run;  // == E
    }
}

__global__ __launch_bounds__(256) void scan_final(const int* __restrict__ cnt,
                                                  const int* __restrict__ blockSumsEx,
                                                  int* __restrict__ rowStart,
                                                  int* __restrict__ rowPos, int Nn) {
    __shared__ int sdata[256];
    int b = blockIdx.x, t = threadIdx.x;
    int base = blockSumsEx[b];
    int vals[4];
    int sum = 0;
    int i0 = b * 1024 + t * 4;
    for (int i = 0; i < 4; ++i) {
        int idx = i0 + i;
        vals[i] = (idx < Nn) ? cnt[idx] : 0;
        sum += vals[i];
    }
    sdata[t] = sum;
    __syncthreads();
    for (int off = 1; off < 256; off <<= 1) {
        int y = (t >= off) ? sdata[t - off] : 0;
        __syncthreads();
        sdata[t] += y;
        __syncthreads();
    }
    int run = base + (sdata[t] - sum);  // exclusive
    for (int i = 0; i < 4; ++i) {
        int idx = i0 + i;
        if (idx < Nn) { rowStart[idx] = run; rowPos[idx] = run; }
        run += vals[i];
    }
}

// ---------------- dinv ----------------
__global__ void dinv_kernel(const int* __restrict__ cnt, float* __restrict__ dinv, int Nn) {
    int i = blockIdx.x * 256 + threadIdx.x;
    if (i < Nn) dinv[i] = rsqrtf((float)cnt[i] + 1.0f);
}

// ---------------- CSR fill (+norm precompute) ----------------
__global__ void fill_kernel(const int* __restrict__ ei, int E, const int* __restrict__ flag,
                            const float* __restrict__ dinv, int* __restrict__ rowPos,
                            int* __restrict__ csrSrc, float* __restrict__ csrNorm) {
    int e = blockIdx.x * 256 + threadIdx.x;
    if (e >= E) return;
    int is64 = *flag;
    int s = edge_src(ei, E, e, is64);
    int d = edge_dst(ei, E, e, is64);
    int p = atomicAdd(&rowPos[d], 1);
    csrSrc[p] = s;
    csrNorm[p] = dinv[s] * dinv[d];
}

// ---------------- weight conversions ----------------
// W1 [512,256] f32 -> W1t [256,512] bf16 (n-major)
__global__ __launch_bounds__(256) void convertW1t_kernel(const float* __restrict__ W1,
                                                         unsigned short* __restrict__ W1t) {
    int id = blockIdx.x * 256 + threadIdx.x;  // 512*256
    int k = id >> 8, n = id & 255;
    W1t[n * 512 + k] = f2bf(W1[id]);
}

// W2 [256,40] f32 -> W2t [48,256] bf16 (n-major, zero-padded n>=40)
__global__ __launch_bounds__(256) void convertW2t_kernel(const float* __restrict__ W2,
                                                         unsigned short* __restrict__ W2t) {
    int id = blockIdx.x * 256 + threadIdx.x;  // 48*256
    if (id >= NPAD * HID) return;
    int n = id / HID, k = id % HID;
    W2t[id] = (n < NCLS) ? f2bf(W2[k * NCLS + n]) : (unsigned short)0;
}

// ---------------- GEMM1 MFMA v3: h1[Mpad,256](bf16) = bf16(X) @ W1t^T ------
// m97 structure: single-buffered 48KB LDS tile, global_load_lds width=16
// staging (whole tile in flight per K-step), 2 barriers per K-step, 4 waves
// each computing a 64x64 output sub-tile. BK=64.
#define BK 64
__global__ __launch_bounds__(256) void gemm1_mfma_kernel(const float* __restrict__ X,
                                                         const unsigned short* __restrict__ W1t,
                                                         unsigned short* __restrict__ h1, int Nn) {
    __shared__ float As[128 * 64];           // 32 KB
    __shared__ unsigned short Bs[128 * 64];  // 16 KB
    const int tid = threadIdx.x;
    const int bm = blockIdx.x * 128;
    const int bn = blockIdx.y * 128;
    const int lane = tid & 63, w = tid >> 6;
    const int wr = (w & 1) * 64, wc = (w >> 1) * 64;
    const int lrow = lane & 15, lq = lane >> 4;

    int aRow[8], aK[8], bRow[4], bK[4];
#pragma unroll
    for (int i = 0; i < 8; ++i) {
        int c = i * 256 + w * 64 + lane;
        int row = c >> 4, pslot = c & 15;
        aRow[i] = row; aK[i] = (pslot ^ (row & 15)) * 4;   // f32 elements
    }
#pragma unroll
    for (int i = 0; i < 4; ++i) {
        int c = i * 256 + w * 64 + lane;
        int row = c >> 3, pslot = c & 7;
        bRow[i] = row; bK[i] = (pslot ^ (row & 7)) * 8;    // bf16 elements
    }

    floatx4 acc[4][4];
#pragma unroll
    for (int i = 0; i < 4; ++i)
#pragma unroll
        for (int j = 0; j < 4; ++j)
            acc[i][j] = (floatx4){0.f, 0.f, 0.f, 0.f};

    for (int t = 0; t < F_IN / BK; ++t) {
        const int k0 = t * BK;
        __syncthreads();   // previous step's fragment reads complete
#pragma unroll
        for (int i = 0; i < 8; ++i) {
            int srow = bm + aRow[i];
            if (srow >= Nn) srow = Nn - 1;   // pad rows: harmless garbage, never read
            gload_lds16(&X[(size_t)srow * F_IN + k0 + aK[i]],
                        &As[(i * 256 + w * 64) * 4]);
        }
#pragma unroll
        for (int i = 0; i < 4; ++i)
            gload_lds16(&W1t[(size_t)(bn + bRow[i]) * F_IN + k0 + bK[i]],
                        &Bs[(i * 256 + w * 64) * 8]);
        __syncthreads();   // compiler drains vmcnt before barrier

#pragma unroll
        for (int kh = 0; kh < 2; ++kh) {
            bf16x8 av[4], bv[4];
#pragma unroll
            for (int mt = 0; mt < 4; ++mt) {
                int row = wr + mt * 16 + lrow;
                int m = row & 15;
                int s0 = kh * 8 + lq * 2;
                float4 f0 = *(const float4*)&As[row * 64 + ((s0 ^ m) << 2)];
                float4 f1 = *(const float4*)&As[row * 64 + (((s0 + 1) ^ m) << 2)];
                av[mt] = pack8(f0, f1);
            }
#pragma unroll
            for (int nt = 0; nt < 4; ++nt) {
                int row = wc + nt * 16 + lrow;
                int ls = kh * 4 + lq;
                bv[nt] = *(const bf16x8*)&Bs[row * 64 + ((ls ^ (row & 7)) << 3)];
            }
#pragma unroll
            for (int mt = 0; mt < 4; ++mt)
#pragma unroll
                for (int nt = 0; nt < 4; ++nt)
                    acc[mt][nt] = __builtin_amdgcn_mfma_f32_16x16x32_bf16(
                        bv[nt], av[mt], acc[mt][nt], 0, 0, 0);
        }
    }

#pragma unroll
    for (int mt = 0; mt < 4; ++mt) {
        size_t gm = (size_t)(bm + wr + mt * 16 + lrow);
#pragma unroll
        for (int nt = 0; nt < 4; ++nt) {
            int gn = bn + wc + nt * 16 + lq * 4;
            ushort4 o;
            o.x = f2bf(acc[mt][nt][0]); o.y = f2bf(acc[mt][nt][1]);
            o.z = f2bf(acc[mt][nt][2]); o.w = f2bf(acc[mt][nt][3]);
            *(ushort4*)&h1[gm * HID + gn] = o;
        }
    }
}

// ---------------- Agg1 + bias + relu: XCD column-sliced gather -------------
// slice = blockIdx.x % 8 -> lands on one XCD (round-robin dispatch); that
// XCD only ever touches 64B of each h1 row -> 6.4MB distinct bytes, L2-hot.
// Wave per (node, slice): 16 edges in flight, 4 lanes/edge, 16B/lane.
#define AGG1_K 3200   // blocks per slice; grid = 8*AGG1_K, grid-stride nodes
__global__ __launch_bounds__(256) void agg1_kernel(const unsigned short* __restrict__ h1,
                                                   const int* __restrict__ rowStart,
                                                   const int* __restrict__ csrSrc,
                                                   const float* __restrict__ csrNorm,
                                                   const float* __restrict__ dinv,
                                                   const float* __restrict__ b1,
                                                   unsigned short* __restrict__ x1b, int Nn) {
    const int slice = blockIdx.x & 7;
    const int bb = blockIdx.x >> 3;
    const int wid = threadIdx.x >> 6;
    const int lane = threadIdx.x & 63;
    const int eg = lane >> 2;          // edge group 0..15
    const int lc = lane & 3;           // 16B sub-chunk within the 64B slice
    const char* hb = (const char*)h1 + slice * 64 + lc * 16;

    // bias for my 8 cols (uniform per lane, cached)
    const int c0 = slice * 32 + lc * 8;
    float bia[8];
#pragma unroll
    for (int j = 0; j < 8; ++j) bia[j] = b1[c0 + j];

    for (int n = bb * 4 + wid; n < Nn; n += AGG1_K * 4) {
        float acc[8];
#pragma unroll
        for (int j = 0; j < 8; ++j) acc[j] = 0.f;
        int s0 = rowStart[n], s1 = rowStart[n + 1];
        for (int e = s0; e + eg < s1; e += 16) {
            int idx = csrSrc[e + eg];
            float nrm = csrNorm[e + eg];
            bf16x8 v = *(const bf16x8*)(hb + (size_t)idx * (HID * 2));
#pragma unroll
            for (int j = 0; j < 8; ++j)
                acc[j] += nrm * bf2f((unsigned short)v[j]);
        }
        // reduce the 16 edge-groups (lanes sharing lc): xor over lane bits 2..5
#pragma unroll
        for (int off = 4; off < 64; off <<= 1)
#pragma unroll
            for (int j = 0; j < 8; ++j) acc[j] += __shfl_xor(acc[j], off);

        if (eg == 0) {
            float di = dinv[n];
            float self = di * di;
            bf16x8 hv = *(const bf16x8*)(hb + (size_t)n * (HID * 2));
            bf16x8 o;
#pragma unroll
            for (int j = 0; j < 8; ++j)
                o[j] = (short)f2bf(fmaxf(acc[j] + self * bf2f((unsigned short)hv[j]) + bia[j], 0.f));
            *(bf16x8*)((char*)x1b + (size_t)n * (HID * 2) + slice * 64 + lc * 16) = o;
        }
    }
}

// ---------------- GEMM2 MFMA: h2b[Mpad,48](bf16) = x1b @ W2t^T -------------
__global__ __launch_bounds__(256) void gemm2_mfma_kernel(const unsigned short* __restrict__ x1b,
                                                         const unsigned short* __restrict__ W2t,
                                                         unsigned short* __restrict__ h2b) {
    const int tid = threadIdx.x;
    const int lane = tid & 63, w = tid >> 6;
    const int base = blockIdx.x * 128 + w * 32;
    const int lrow = lane & 15, lq = lane >> 4;

    floatx4 acc[2][3];
#pragma unroll
    for (int i = 0; i < 2; ++i)
#pragma unroll
        for (int j = 0; j < 3; ++j)
            acc[i][j] = (floatx4){0.f, 0.f, 0.f, 0.f};

#pragma unroll
    for (int k0 = 0; k0 < HID; k0 += 32) {
        bf16x8 a[2], b[3];
#pragma unroll
        for (int mt = 0; mt < 2; ++mt)
            a[mt] = *(const bf16x8*)&x1b[(size_t)(base + mt * 16 + lrow) * HID + k0 + lq * 8];
#pragma unroll
        for (int nt = 0; nt < 3; ++nt)
            b[nt] = *(const bf16x8*)&W2t[(size_t)(nt * 16 + lrow) * HID + k0 + lq * 8];
        // swapped operands: acc[mt][nt][r] = C[base+mt*16+lrow][nt*16+lq*4+r]
#pragma unroll
        for (int mt = 0; mt < 2; ++mt)
#pragma unroll
            for (int nt = 0; nt < 3; ++nt)
                acc[mt][nt] = __builtin_amdgcn_mfma_f32_16x16x32_bf16(
                    b[nt], a[mt], acc[mt][nt], 0, 0, 0);
    }
#pragma unroll
    for (int mt = 0; mt < 2; ++mt) {
        size_t gm = (size_t)(base + mt * 16 + lrow);
#pragma unroll
        for (int nt = 0; nt < 3; ++nt) {
            int gn = nt * 16 + lq * 4;
            ushort4 o;
            o.x = f2bf(acc[mt][nt][0]); o.y = f2bf(acc[mt][nt][1]);
            o.z = f2bf(acc[mt][nt][2]); o.w = f2bf(acc[mt][nt][3]);
            *(ushort4*)&h2b[gm * NPAD + gn] = o;
        }
    }
}

// ---------------- Agg2 + bias + softmax/log_softmax, unroll x4 -------------
__global__ __launch_bounds__(256) void agg2_kernel(const unsigned short* __restrict__ h2b,
                                                   const int* __restrict__ rowStart,
                                                   const int* __restrict__ csrSrc,
                                                   const float* __restrict__ csrNorm,
                                                   const float* __restrict__ dinv,
                                                   const float* __restrict__ b2,
                                                   float* __restrict__ out, int Nn) {
    int n = blockIdx.x * 4 + (threadIdx.x >> 6);
    int lane = threadIdx.x & 63;
    if (n >= Nn) return;
    bool act = lane < NCLS;
    int cl = act ? lane : 0;
    float acc = 0.f;
    int s0 = rowStart[n], s1 = rowStart[n + 1];
    int e = s0;
    for (; e + 3 < s1; e += 4) {
        int iA = csrSrc[e], iB = csrSrc[e + 1], iC = csrSrc[e + 2], iD = csrSrc[e + 3];
        float nA = csrNorm[e], nB = csrNorm[e + 1], nC = csrNorm[e + 2], nD = csrNorm[e + 3];
        float vA = bf2f(h2b[(size_t)iA * NPAD + cl]);
        float vB = bf2f(h2b[(size_t)iB * NPAD + cl]);
        float vC = bf2f(h2b[(size_t)iC * NPAD + cl]);
        float vD = bf2f(h2b[(size_t)iD * NPAD + cl]);
        acc += nA * vA + nB * vB + nC * vC + nD * vD;
    }
    for (; e < s1; ++e) {
        int s = csrSrc[e];
        acc += csrNorm[e] * bf2f(h2b[(size_t)s * NPAD + cl]);
    }
    float di = dinv[n];
    acc += di * di * bf2f(h2b[(size_t)n * NPAD + cl]) + b2[cl];
    float v = act ? acc : -3.4e38f;
#pragma unroll
    for (int off = 32; off > 0; off >>= 1) v = fmaxf(v, __shfl_xor(v, off));
    float ex = act ? expf(acc - v) : 0.f;
    float ssum = ex;
#pragma unroll
    for (int off = 32; off > 0; off >>= 1) ssum += __shfl_xor(ssum, off);
    if (act) {
        float ls = acc - v - logf(ssum);
        out[(size_t)n * NCLS + lane] = ls;                             // log_softmax
        out[(size_t)Nn * NCLS + (size_t)n * NCLS + lane] = ex / ssum;  // softmax
    }
}

// ---------------------------------------------------------------------------
extern "C" void kernel_launch(void* const* d_in, const int* in_sizes, int n_in,
                              void* d_out, int out_size, void* d_ws, size_t ws_size,
                              hipStream_t stream) {
    const float* features = (const float*)d_in[0];
    const float* W1 = (const float*)d_in[1];
    const float* b1 = (const float*)d_in[2];
    const float* W2 = (const float*)d_in[3];
    const float* b2 = (const float*)d_in[4];
    const int* edge_index = (const int*)d_in[5];

    const int N = in_sizes[0] / F_IN;        // 100000
    const int E = in_sizes[5] / 2;           // 1600000
    const int Mpad = (N + 127) & ~127;       // 100096
    float* out = (float*)d_out;

    auto align256 = [](size_t x) { return (x + 255) & ~(size_t)255; };
    char* w = (char*)d_ws;
    int* cnt        = (int*)w;  w += align256((size_t)N * 4);
    int* rowStart   = (int*)w;  w += align256((size_t)(N + 1) * 4);
    int* rowPos     = (int*)w;  w += align256((size_t)N * 4);
    int* blockSums  = (int*)w;  w += align256(1024 * 4);
    int* flag64     = (int*)w;  w += 256;
    int* csrSrc     = (int*)w;  w += align256((size_t)E * 4);
    float* csrNorm  = (float*)w; w += align256((size_t)E * 4);
    float* dinv     = (float*)w; w += align256((size_t)N * 4);
    unsigned short* W1t = (unsigned short*)w; w += align256((size_t)HID * F_IN * 2);
    unsigned short* W2t = (unsigned short*)w; w += align256((size_t)NPAD * HID * 2);
    unsigned short* h1  = (unsigned short*)w; w += align256((size_t)Mpad * HID * 2);
    unsigned short* x1b = (unsigned short*)w; w += align256((size_t)Mpad * HID * 2);
    unsigned short* h2b = (unsigned short*)w; w += align256((size_t)Mpad * NPAD * 2);
    (void)ws_size;

    const int nB = (N + 1023) / 1024;
    const int eBlocks = (E + 255) / 256;
    const int nBlocks = (N + 255) / 256;
    const int waveBlocks = (N + 3) / 4;

    hipMemsetAsync(cnt, 0, (size_t)N * 4, stream);
    detect64_kernel<<<1, 256, 0, stream>>>(edge_index, flag64);
    count_kernel<<<eBlocks, 256, 0, stream>>>(edge_index, E, flag64, cnt);
    scan_block_sums<<<nB, 256, 0, stream>>>(cnt, blockSums, N);
    scan_sums_kernel<<<1, 64, 0, stream>>>(blockSums, nB, rowStart, N);
    dinv_kernel<<<nBlocks, 256, 0, stream>>>(cnt, dinv, N);
    scan_final<<<nB, 256, 0, stream>>>(cnt, blockSums, rowStart, rowPos, N);
    fill_kernel<<<eBlocks, 256, 0, stream>>>(edge_index, E, flag64, dinv, rowPos,
                                             csrSrc, csrNorm);

    convertW1t_kernel<<<(F_IN * HID) / 256, 256, 0, stream>>>(W1, W1t);
    convertW2t_kernel<<<(NPAD * HID + 255) / 256, 256, 0, stream>>>(W2, W2t);

    dim3 g1(Mpad / 128, HID / 128);
    gemm1_mfma_kernel<<<g1, 256, 0, stream>>>(features, W1t, h1, N);
    agg1_kernel<<<8 * AGG1_K, 256, 0, stream>>>(h1, rowStart, csrSrc, csrNorm, dinv,
                                                b1, x1b, N);
    gemm2_mfma_kernel<<<Mpad / 128, 256, 0, stream>>>(x1b, W2t, h2b);
    agg2_kernel<<<waveBlocks, 256, 0, stream>>>(h2b, rowStart, csrSrc, csrNorm, dinv,
                                                b2, out, N);
}

// Round 7
// 739.734 us; speedup vs baseline: 1.2128x; 1.2128x over previous
//
#include <hip/hip_runtime.h>
#include <hip/hip_bf16.h>

// ---------------------------------------------------------------------------
// GCN 2-layer forward (f32 in/out), MFMA bf16 GEMMs:
//   x1 = relu( Ahat @ (X W1) + b1 ),  out = Ahat @ (x1 W2) + b2
//   return log_softmax(out), softmax(out)
// Round 12: the fused agg1+gemm2 source failed the container 4x (2 rounds x
// 2 attempts) -- likely source-triggered despite passing audit. De-risk:
// back to the round-8 source (clean 741us bench), one minimal change: agg1
// keeps 16 edges in flight per wave (was 8) -- h1 is L3-resident (51MB <
// 256MB), the 407MB L2-miss gather runs at 3.4TB/s fabric rate, so if the
// limiter is request concurrency this doubles per-wave outstanding loads.
// ---------------------------------------------------------------------------

#define F_IN 512
#define HID  256
#define NCLS 40
#define NPAD 48

typedef __attribute__((ext_vector_type(8))) short bf16x8;
typedef __attribute__((ext_vector_type(4))) float floatx4;

__device__ inline unsigned short f2bf(float v) {
    unsigned u = __float_as_uint(v);
    u += 0x7fffu + ((u >> 16) & 1u);   // round-to-nearest-even
    return (unsigned short)(u >> 16);
}
__device__ inline float bf2f(unsigned short u) {
    return __uint_as_float(((unsigned)u) << 16);
}

__device__ inline void gload_lds16(const void* g, void* l) {
    __builtin_amdgcn_global_load_lds(
        (const __attribute__((address_space(1))) unsigned int*)g,
        (__attribute__((address_space(3))) unsigned int*)l, 16, 0, 0);
}

__device__ inline bf16x8 pack8(float4 f0, float4 f1) {
    bf16x8 r;
    r[0] = (short)f2bf(f0.x); r[1] = (short)f2bf(f0.y);
    r[2] = (short)f2bf(f0.z); r[3] = (short)f2bf(f0.w);
    r[4] = (short)f2bf(f1.x); r[5] = (short)f2bf(f1.y);
    r[6] = (short)f2bf(f1.z); r[7] = (short)f2bf(f1.w);
    return r;
}

// ---------------- edge dtype detect (int64 vs int32) ----------------
__global__ void detect64_kernel(const int* __restrict__ ei, int* __restrict__ flag) {
    __shared__ int any_nz;
    if (threadIdx.x == 0) any_nz = 0;
    __syncthreads();
    int nz = 0;
    for (int i = threadIdx.x; i < 4096; i += 256) {
        nz |= (ei[2 * i + 1] != 0);
    }
    if (nz) atomicOr(&any_nz, 1);
    __syncthreads();
    if (threadIdx.x == 0) *flag = any_nz ? 0 : 1;  // 1 => int64 layout
}

__device__ inline int edge_src(const int* ei, long long E, int e, int is64) {
    return is64 ? ei[2LL * e] : ei[e];
}
__device__ inline int edge_dst(const int* ei, long long E, int e, int is64) {
    return is64 ? ei[2LL * (E + e)] : ei[(int)E + e];
}

// ---------------- degree count ----------------
__global__ void count_kernel(const int* __restrict__ ei, int E,
                             const int* __restrict__ flag, int* __restrict__ cnt) {
    int e = blockIdx.x * 256 + threadIdx.x;
    if (e >= E) return;
    int is64 = *flag;
    int d = edge_dst(ei, E, e, is64);
    atomicAdd(&cnt[d], 1);
}

// ---------------- scan (3-phase) ----------------
__global__ __launch_bounds__(256) void scan_block_sums(const int* __restrict__ cnt,
                                                       int* __restrict__ blockSums, int Nn) {
    __shared__ int sdata[256];
    int b = blockIdx.x, t = threadIdx.x;
    int sum = 0;
    int i0 = b * 1024 + t * 4;
    for (int i = 0; i < 4; ++i) {
        int idx = i0 + i;
        if (idx < Nn) sum += cnt[idx];
    }
    sdata[t] = sum;
    __syncthreads();
    for (int s = 128; s > 0; s >>= 1) {
        if (t < s) sdata[t] += sdata[t + s];
        __syncthreads();
    }
    if (t == 0) blockSums[b] = sdata[0];
}

__global__ void scan_sums_kernel(int* __restrict__ blockSums, int nB,
                                 int* __restrict__ rowStart, int Nn) {
    if (threadIdx.x == 0 && blockIdx.x == 0) {
        int run = 0;
        for (int i = 0; i < nB; ++i) { int v = blockSums[i]; blockSums[i] = run; run += v; }
        rowStart[Nn] = run;  // == E
    }
}

__global__ __launch_bounds__(256) void scan_final(const int* __restrict__ cnt,
                                                  const int* __restrict__ blockSumsEx,
                                                  int* __restrict__ rowStart,
                                                  int* __restrict__ rowPos, int Nn) {
    __shared__ int sdata[256];
    int b = blockIdx.x, t = threadIdx.x;
    int base = blockSumsEx[b];
    int vals[4];
    int sum = 0;
    int i0 = b * 1024 + t * 4;
    for (int i = 0; i < 4; ++i) {
        int idx = i0 + i;
        vals[i] = (idx < Nn) ? cnt[idx] : 0;
        sum += vals[i];
    }
    sdata[t] = sum;
    __syncthreads();
    for (int off = 1; off < 256; off <<= 1) {
        int y = (t >= off) ? sdata[t - off] : 0;
        __syncthreads();
        sdata[t] += y;
        __syncthreads();
    }
    int run = base + (sdata[t] - sum);  // exclusive
    for (int i = 0; i < 4; ++i) {
        int idx = i0 + i;
        if (idx < Nn) { rowStart[idx] = run; rowPos[idx] = run; }
        run += vals[i];
    }
}

// ---------------- dinv ----------------
__global__ void dinv_kernel(const int* __restrict__ cnt, float* __restrict__ dinv, int Nn) {
    int i = blockIdx.x * 256 + threadIdx.x;
    if (i < Nn) dinv[i] = rsqrtf((float)cnt[i] + 1.0f);
}

// ---------------- CSR fill (+norm precompute) ----------------
__global__ void fill_kernel(const int* __restrict__ ei, int E, const int* __restrict__ flag,
                            const float* __restrict__ dinv, int* __restrict__ rowPos,
                            int* __restrict__ csrSrc, float* __restrict__ csrNorm) {
    int e = blockIdx.x * 256 + threadIdx.x;
    if (e >= E) return;
    int is64 = *flag;
    int s = edge_src(ei, E, e, is64);
    int d = edge_dst(ei, E, e, is64);
    int p = atomicAdd(&rowPos[d], 1);
    csrSrc[p] = s;
    csrNorm[p] = dinv[s] * dinv[d];
}

// ---------------- weight conversions ----------------
// W1 [512,256] f32 -> W1t [256,512] bf16 (n-major)
__global__ __launch_bounds__(256) void convertW1t_kernel(const float* __restrict__ W1,
                                                         unsigned short* __restrict__ W1t) {
    int id = blockIdx.x * 256 + threadIdx.x;  // 512*256
    int k = id >> 8, n = id & 255;
    W1t[n * 512 + k] = f2bf(W1[id]);
}

// W2 [256,40] f32 -> W2t [48,256] bf16 (n-major, zero-padded n>=40)
__global__ __launch_bounds__(256) void convertW2t_kernel(const float* __restrict__ W2,
                                                         unsigned short* __restrict__ W2t) {
    int id = blockIdx.x * 256 + threadIdx.x;  // 48*256
    if (id >= NPAD * HID) return;
    int n = id / HID, k = id % HID;
    W2t[id] = (n < NCLS) ? f2bf(W2[k * NCLS + n]) : (unsigned short)0;
}

// ---------------- GEMM1 MFMA v3: h1[Mpad,256](bf16) = bf16(X) @ W1t^T ------
// m97 structure: single-buffered 48KB LDS tile, global_load_lds width=16
// staging (whole tile in flight per K-step), 2 barriers per K-step, 4 waves
// each computing a 64x64 output sub-tile. BK=64.
#define BK 64
__global__ __launch_bounds__(256) void gemm1_mfma_kernel(const float* __restrict__ X,
                                                         const unsigned short* __restrict__ W1t,
                                                         unsigned short* __restrict__ h1, int Nn) {
    __shared__ float As[128 * 64];           // 32 KB
    __shared__ unsigned short Bs[128 * 64];  // 16 KB
    const int tid = threadIdx.x;
    const int bm = blockIdx.x * 128;
    const int bn = blockIdx.y * 128;
    const int lane = tid & 63, w = tid >> 6;
    const int wr = (w & 1) * 64, wc = (w >> 1) * 64;
    const int lrow = lane & 15, lq = lane >> 4;

    int aRow[8], aK[8], bRow[4], bK[4];
#pragma unroll
    for (int i = 0; i < 8; ++i) {
        int c = i * 256 + w * 64 + lane;
        int row = c >> 4, pslot = c & 15;
        aRow[i] = row; aK[i] = (pslot ^ (row & 15)) * 4;   // f32 elements
    }
#pragma unroll
    for (int i = 0; i < 4; ++i) {
        int c = i * 256 + w * 64 + lane;
        int row = c >> 3, pslot = c & 7;
        bRow[i] = row; bK[i] = (pslot ^ (row & 7)) * 8;    // bf16 elements
    }

    floatx4 acc[4][4];
#pragma unroll
    for (int i = 0; i < 4; ++i)
#pragma unroll
        for (int j = 0; j < 4; ++j)
            acc[i][j] = (floatx4){0.f, 0.f, 0.f, 0.f};

    for (int t = 0; t < F_IN / BK; ++t) {
        const int k0 = t * BK;
        __syncthreads();   // previous step's fragment reads complete
#pragma unroll
        for (int i = 0; i < 8; ++i) {
            int srow = bm + aRow[i];
            if (srow >= Nn) srow = Nn - 1;   // pad rows: harmless garbage, never read
            gload_lds16(&X[(size_t)srow * F_IN + k0 + aK[i]],
                        &As[(i * 256 + w * 64) * 4]);
        }
#pragma unroll
        for (int i = 0; i < 4; ++i)
            gload_lds16(&W1t[(size_t)(bn + bRow[i]) * F_IN + k0 + bK[i]],
                        &Bs[(i * 256 + w * 64) * 8]);
        __syncthreads();   // compiler drains vmcnt before barrier

#pragma unroll
        for (int kh = 0; kh < 2; ++kh) {
            bf16x8 av[4], bv[4];
#pragma unroll
            for (int mt = 0; mt < 4; ++mt) {
                int row = wr + mt * 16 + lrow;
                int m = row & 15;
                int s0 = kh * 8 + lq * 2;
                float4 f0 = *(const float4*)&As[row * 64 + ((s0 ^ m) << 2)];
                float4 f1 = *(const float4*)&As[row * 64 + (((s0 + 1) ^ m) << 2)];
                av[mt] = pack8(f0, f1);
            }
#pragma unroll
            for (int nt = 0; nt < 4; ++nt) {
                int row = wc + nt * 16 + lrow;
                int ls = kh * 4 + lq;
                bv[nt] = *(const bf16x8*)&Bs[row * 64 + ((ls ^ (row & 7)) << 3)];
            }
#pragma unroll
            for (int mt = 0; mt < 4; ++mt)
#pragma unroll
                for (int nt = 0; nt < 4; ++nt)
                    acc[mt][nt] = __builtin_amdgcn_mfma_f32_16x16x32_bf16(
                        bv[nt], av[mt], acc[mt][nt], 0, 0, 0);
        }
    }

#pragma unroll
    for (int mt = 0; mt < 4; ++mt) {
        size_t gm = (size_t)(bm + wr + mt * 16 + lrow);
#pragma unroll
        for (int nt = 0; nt < 4; ++nt) {
            int gn = bn + wc + nt * 16 + lq * 4;
            ushort4 o;
            o.x = f2bf(acc[mt][nt][0]); o.y = f2bf(acc[mt][nt][1]);
            o.z = f2bf(acc[mt][nt][2]); o.w = f2bf(acc[mt][nt][3]);
            *(ushort4*)&h1[gm * HID + gn] = o;
        }
    }
}

// ---------------- Agg1 + bias + relu: edge-pair gather, 16 in flight -------
// Wave per node. Lanes 0-31 process even edges, lanes 32-63 odd edges; each
// lane owns 8 bf16 cols (16B dwordx4 gather). 8 pairs (16 edges) in flight.
__global__ __launch_bounds__(256) void agg1_kernel(const unsigned short* __restrict__ h1,
                                                   const int* __restrict__ rowStart,
                                                   const int* __restrict__ csrSrc,
                                                   const float* __restrict__ csrNorm,
                                                   const float* __restrict__ dinv,
                                                   const float* __restrict__ b1,
                                                   unsigned short* __restrict__ x1b, int Nn) {
    int n = blockIdx.x * 4 + (threadIdx.x >> 6);
    int lane = threadIdx.x & 63;
    if (n >= Nn) return;
    const int half = lane >> 5;           // 0: even edge of pair, 1: odd
    const int col = lane & 31;            // owns bf16 cols col*8 .. col*8+7
    const char* hb = (const char*)h1 + col * 16;

    float acc[8];
#pragma unroll
    for (int j = 0; j < 8; ++j) acc[j] = 0.f;

    int s0 = rowStart[n], s1 = rowStart[n + 1];
    int e = s0;
    for (; e + 15 < s1; e += 16) {
#pragma unroll
        for (int p = 0; p < 8; ++p) {
            int idx = csrSrc[e + 2 * p + half];
            float nrm = csrNorm[e + 2 * p + half];
            bf16x8 v = *(const bf16x8*)(hb + (unsigned)idx * (unsigned)(HID * 2));
#pragma unroll
            for (int j = 0; j < 8; ++j)
                acc[j] += nrm * bf2f((unsigned short)v[j]);
        }
    }
    for (; e + 1 < s1; e += 2) {
        int idx = csrSrc[e + half];
        float nrm = csrNorm[e + half];
        bf16x8 v = *(const bf16x8*)(hb + (unsigned)idx * (unsigned)(HID * 2));
#pragma unroll
        for (int j = 0; j < 8; ++j)
            acc[j] += nrm * bf2f((unsigned short)v[j]);
    }
    if (e < s1) {  // last unpaired edge: half 1 contributes 0 (same address)
        int idx = csrSrc[e];
        float nrm = half ? 0.f : csrNorm[e];
        bf16x8 v = *(const bf16x8*)(hb + (unsigned)idx * (unsigned)(HID * 2));
#pragma unroll
        for (int j = 0; j < 8; ++j)
            acc[j] += nrm * bf2f((unsigned short)v[j]);
    }

    // combine even/odd halves: lane i + lane i^32 hold the same cols
#pragma unroll
    for (int j = 0; j < 8; ++j) acc[j] += __shfl_xor(acc[j], 32);

    if (half == 0) {
        float di = dinv[n];
        float self = di * di;
        bf16x8 hv = *(const bf16x8*)(hb + (unsigned)n * (unsigned)(HID * 2));
        float4 bv0 = *(const float4*)(b1 + col * 8);
        float4 bv1 = *(const float4*)(b1 + col * 8 + 4);
        float bb[8] = {bv0.x, bv0.y, bv0.z, bv0.w, bv1.x, bv1.y, bv1.z, bv1.w};
        bf16x8 o;
#pragma unroll
        for (int j = 0; j < 8; ++j)
            o[j] = (short)f2bf(fmaxf(acc[j] + self * bf2f((unsigned short)hv[j]) + bb[j], 0.f));
        *(bf16x8*)((char*)x1b + (size_t)n * (HID * 2) + col * 16) = o;
    }
}

// ---------------- GEMM2 MFMA: h2b[Mpad,48](bf16) = x1b @ W2t^T -------------
__global__ __launch_bounds__(256) void gemm2_mfma_kernel(const unsigned short* __restrict__ x1b,
                                                         const unsigned short* __restrict__ W2t,
                                                         unsigned short* __restrict__ h2b) {
    const int tid = threadIdx.x;
    const int lane = tid & 63, w = tid >> 6;
    const int base = blockIdx.x * 128 + w * 32;
    const int lrow = lane & 15, lq = lane >> 4;

    floatx4 acc[2][3];
#pragma unroll
    for (int i = 0; i < 2; ++i)
#pragma unroll
        for (int j = 0; j < 3; ++j)
            acc[i][j] = (floatx4){0.f, 0.f, 0.f, 0.f};

#pragma unroll
    for (int k0 = 0; k0 < HID; k0 += 32) {
        bf16x8 a[2], b[3];
#pragma unroll
        for (int mt = 0; mt < 2; ++mt)
            a[mt] = *(const bf16x8*)&x1b[(size_t)(base + mt * 16 + lrow) * HID + k0 + lq * 8];
#pragma unroll
        for (int nt = 0; nt < 3; ++nt)
            b[nt] = *(const bf16x8*)&W2t[(size_t)(nt * 16 + lrow) * HID + k0 + lq * 8];
        // swapped operands: acc[mt][nt][r] = C[base+mt*16+lrow][nt*16+lq*4+r]
#pragma unroll
        for (int mt = 0; mt < 2; ++mt)
#pragma unroll
            for (int nt = 0; nt < 3; ++nt)
                acc[mt][nt] = __builtin_amdgcn_mfma_f32_16x16x32_bf16(
                    b[nt], a[mt], acc[mt][nt], 0, 0, 0);
    }
#pragma unroll
    for (int mt = 0; mt < 2; ++mt) {
        size_t gm = (size_t)(base + mt * 16 + lrow);
#pragma unroll
        for (int nt = 0; nt < 3; ++nt) {
            int gn = nt * 16 + lq * 4;
            ushort4 o;
            o.x = f2bf(acc[mt][nt][0]); o.y = f2bf(acc[mt][nt][1]);
            o.z = f2bf(acc[mt][nt][2]); o.w = f2bf(acc[mt][nt][3]);
            *(ushort4*)&h2b[gm * NPAD + gn] = o;
        }
    }
}

// ---------------- Agg2 + bias + softmax/log_softmax, unroll x4 -------------
__global__ __launch_bounds__(256) void agg2_kernel(const unsigned short* __restrict__ h2b,
                                                   const int* __restrict__ rowStart,
                                                   const int* __restrict__ csrSrc,
                                                   const float* __restrict__ csrNorm,
                                                   const float* __restrict__ dinv,
                                                   const float* __restrict__ b2,
                                                   float* __restrict__ out, int Nn) {
    int n = blockIdx.x * 4 + (threadIdx.x >> 6);
    int lane = threadIdx.x & 63;
    if (n >= Nn) return;
    bool act = lane < NCLS;
    int cl = act ? lane : 0;
    float acc = 0.f;
    int s0 = rowStart[n], s1 = rowStart[n + 1];
    int e = s0;
    for (; e + 3 < s1; e += 4) {
        int iA = csrSrc[e], iB = csrSrc[e + 1], iC = csrSrc[e + 2], iD = csrSrc[e + 3];
        float nA = csrNorm[e], nB = csrNorm[e + 1], nC = csrNorm[e + 2], nD = csrNorm[e + 3];
        float vA = bf2f(h2b[(size_t)iA * NPAD + cl]);
        float vB = bf2f(h2b[(size_t)iB * NPAD + cl]);
        float vC = bf2f(h2b[(size_t)iC * NPAD + cl]);
        float vD = bf2f(h2b[(size_t)iD * NPAD + cl]);
        acc += nA * vA + nB * vB + nC * vC + nD * vD;
    }
    for (; e < s1; ++e) {
        int s = csrSrc[e];
        acc += csrNorm[e] * bf2f(h2b[(size_t)s * NPAD + cl]);
    }
    float di = dinv[n];
    acc += di * di * bf2f(h2b[(size_t)n * NPAD + cl]) + b2[cl];
    float v = act ? acc : -3.4e38f;
#pragma unroll
    for (int off = 32; off > 0; off >>= 1) v = fmaxf(v, __shfl_xor(v, off));
    float ex = act ? expf(acc - v) : 0.f;
    float ssum = ex;
#pragma unroll
    for (int off = 32; off > 0; off >>= 1) ssum += __shfl_xor(ssum, off);
    if (act) {
        float ls = acc - v - logf(ssum);
        out[(size_t)n * NCLS + lane] = ls;                             // log_softmax
        out[(size_t)Nn * NCLS + (size_t)n * NCLS + lane] = ex / ssum;  // softmax
    }
}

// ---------------------------------------------------------------------------
extern "C" void kernel_launch(void* const* d_in, const int* in_sizes, int n_in,
                              void* d_out, int out_size, void* d_ws, size_t ws_size,
                              hipStream_t stream) {
    const float* features = (const float*)d_in[0];
    const float* W1 = (const float*)d_in[1];
    const float* b1 = (const float*)d_in[2];
    const float* W2 = (const float*)d_in[3];
    const float* b2 = (const float*)d_in[4];
    const int* edge_index = (const int*)d_in[5];

    const int N = in_sizes[0] / F_IN;        // 100000
    const int E = in_sizes[5] / 2;           // 1600000
    const int Mpad = (N + 127) & ~127;       // 100096
    float* out = (float*)d_out;

    auto align256 = [](size_t x) { return (x + 255) & ~(size_t)255; };
    char* w = (char*)d_ws;
    int* cnt        = (int*)w;  w += align256((size_t)N * 4);
    int* rowStart   = (int*)w;  w += align256((size_t)(N + 1) * 4);
    int* rowPos     = (int*)w;  w += align256((size_t)N * 4);
    int* blockSums  = (int*)w;  w += align256(1024 * 4);
    int* flag64     = (int*)w;  w += 256;
    int* csrSrc     = (int*)w;  w += align256((size_t)E * 4);
    float* csrNorm  = (float*)w; w += align256((size_t)E * 4);
    float* dinv     = (float*)w; w += align256((size_t)N * 4);
    unsigned short* W1t = (unsigned short*)w; w += align256((size_t)HID * F_IN * 2);
    unsigned short* W2t = (unsigned short*)w; w += align256((size_t)NPAD * HID * 2);
    unsigned short* h1  = (unsigned short*)w; w += align256((size_t)Mpad * HID * 2);
    unsigned short* x1b = (unsigned short*)w; w += align256((size_t)Mpad * HID * 2);
    unsigned short* h2b = (unsigned short*)w; w += align256((size_t)Mpad * NPAD * 2);
    (void)ws_size;

    const int nB = (N + 1023) / 1024;
    const int eBlocks = (E + 255) / 256;
    const int nBlocks = (N + 255) / 256;
    const int waveBlocks = (N + 3) / 4;

    hipMemsetAsync(cnt, 0, (size_t)N * 4, stream);
    detect64_kernel<<<1, 256, 0, stream>>>(edge_index, flag64);
    count_kernel<<<eBlocks, 256, 0, stream>>>(edge_index, E, flag64, cnt);
    scan_block_sums<<<nB, 256, 0, stream>>>(cnt, blockSums, N);
    scan_sums_kernel<<<1, 64, 0, stream>>>(blockSums, nB, rowStart, N);
    dinv_kernel<<<nBlocks, 256, 0, stream>>>(cnt, dinv, N);
    scan_final<<<nB, 256, 0, stream>>>(cnt, blockSums, rowStart, rowPos, N);
    fill_kernel<<<eBlocks, 256, 0, stream>>>(edge_index, E, flag64, dinv, rowPos,
                                             csrSrc, csrNorm);

    convertW1t_kernel<<<(F_IN * HID) / 256, 256, 0, stream>>>(W1, W1t);
    convertW2t_kernel<<<(NPAD * HID + 255) / 256, 256, 0, stream>>>(W2, W2t);

    dim3 g1(Mpad / 128, HID / 128);
    gemm1_mfma_kernel<<<g1, 256, 0, stream>>>(features, W1t, h1, N);
    agg1_kernel<<<waveBlocks, 256, 0, stream>>>(h1, rowStart, csrSrc, csrNorm, dinv,
                                                b1, x1b, N);
    gemm2_mfma_kernel<<<Mpad / 128, 256, 0, stream>>>(x1b, W2t, h2b);
    agg2_kernel<<<waveBlocks, 256, 0, stream>>>(h2b, rowStart, csrSrc, csrNorm, dinv,
                                                b2, out, N);
}